// Round 3
// baseline (270.743 us; speedup 1.0000x reference)
//
#include <hip/hip_runtime.h>

typedef unsigned short u16;
typedef __attribute__((ext_vector_type(8))) short short8;
typedef __attribute__((ext_vector_type(4))) float f32x4;
typedef __attribute__((ext_vector_type(4))) u16 u16x4;

#define F 256

__device__ __forceinline__ u16 f2bf(float f) {
  unsigned u = __float_as_uint(f);
  unsigned r = u + 0x7fffu + ((u >> 16) & 1u);
  return (u16)(r >> 16);
}

__device__ __forceinline__ f32x4 bf4_to_f32(u16x4 u) {
  f32x4 x;
#pragma unroll
  for (int j = 0; j < 4; j++) x[j] = __uint_as_float((unsigned)u[j] << 16);
  return x;
}

// ---- GEMM body: y = x @ W^T, bf16 out in FEATURE-SPLIT layout ----
// y layout: yb[((fb*NN + node) * 32) + fi], fb = feature>>5, fi = feature&31.
// 64B per (node, fb) -> one XCD's slice (all nodes, one fb) = 3.2 MB, fits
// the 4 MB per-XCD L2. Gather pins fb k to XCD k so y reads become L2 hits.
__device__ __forceinline__ void gemm_body(const float* __restrict__ x,
                                          const float* __restrict__ Wm,
                                          u16* __restrict__ yb,
                                          int NT, int NN, int gidx, int stride) {
  int w = (int)(threadIdx.x >> 6);
  int lane = threadIdx.x & 63;
  int ln = lane & 15, q = lane >> 4;

  short8 Bf[4][8];
#pragma unroll
  for (int j = 0; j < 4; j++) {
#pragma unroll
    for (int t = 0; t < 8; t++) {
      const f32x4* wp = (const f32x4*)(Wm + (size_t)((4 * w + j) * 16 + ln) * F + t * 32 + q * 8);
      f32x4 wlo = wp[0], whi = wp[1];
      short8 bfrag;
#pragma unroll
      for (int i = 0; i < 4; i++) {
        bfrag[i]     = (short)f2bf(wlo[i]);
        bfrag[4 + i] = (short)f2bf(whi[i]);
      }
      Bf[j][t] = bfrag;
    }
  }

  for (int mt = gidx; mt < NT; mt += stride) {
    const float* arow = x + (size_t)(mt * 16 + ln) * F + q * 8;
    f32x4 acc[4];
#pragma unroll
    for (int j = 0; j < 4; j++) acc[j] = (f32x4){0.f, 0.f, 0.f, 0.f};

#pragma unroll
    for (int t = 0; t < 8; t++) {
      const f32x4* a4 = (const f32x4*)(arow + t * 32);
      f32x4 alo = a4[0], ahi = a4[1];
      short8 a;
#pragma unroll
      for (int j = 0; j < 4; j++) {
        a[j]     = (short)f2bf(alo[j]);
        a[4 + j] = (short)f2bf(ahi[j]);
      }
#pragma unroll
      for (int j = 0; j < 4; j++) {
        acc[j] = __builtin_amdgcn_mfma_f32_16x16x32_bf16(a, Bf[j][t], acc[j], 0, 0, 0);
      }
    }

    int m0 = mt * 16;
#pragma unroll
    for (int j = 0; j < 4; j++) {
      int fb = 2 * w + (j >> 1);
      int fi = ((j & 1) << 4) + ln;
#pragma unroll
      for (int r = 0; r < 4; r++) {
        yb[((size_t)fb * NN + (m0 + q * 4 + r)) * 32 + fi] = f2bf(acc[j][r]);
      }
    }
  }
}

__global__ void __launch_bounds__(256, 1) gemm_only_k(const float* __restrict__ x,
                                                      const float* __restrict__ Wm,
                                                      u16* __restrict__ yb, int NT, int NN,
                                                      int stride) {
  gemm_body(x, Wm, yb, NT, NN, blockIdx.x, stride);
}

// 1 edge/thread; counters padded to one per 64B line (r<<4)
__global__ void __launch_bounds__(256) scatter_k(const int* __restrict__ erow,
                                                 const int* __restrict__ ecol,
                                                 const float* __restrict__ eval,
                                                 int* __restrict__ curp,
                                                 int2* __restrict__ epk, int E, int CAP) {
  int e = blockIdx.x * 256 + (int)threadIdx.x;
  if (e < E) {
    int r = erow[e];
    int p = atomicAdd(&curp[r << 4], 1);
    if (p < CAP) epk[(size_t)r * CAP + p] = make_int2(ecol[e], __float_as_int(eval[e]));
  }
}

// Feature-split gather: block handles 32 nodes x 1 feature-block (32 feats).
// fb = blockIdx % 8 == XCD id (round-robin mapping), so each XCD only reads
// its own 3.2 MB y-slice -> L2-resident. 8-lane group per node: per edge one
// 64B y-line load (u16x4 x 8 lanes); metas read 8-at-a-time (one 64B line),
// broadcast within the group via __shfl.
__global__ void __launch_bounds__(256) gather_fb_k(const int* __restrict__ curp,
                                                   const int2* __restrict__ epk,
                                                   const u16* __restrict__ yb,
                                                   const float* __restrict__ bias,
                                                   float* __restrict__ out, int NN) {
  int bid = (int)blockIdx.x;
  int fb = bid & 7;
  int nblk = bid >> 3;
  int t = (int)threadIdx.x;
  int g = t >> 3;            // node slot within block: 0..31
  int l8 = t & 7;            // lane within group
  int lw = (t & 63) & ~7;    // group base lane within wave (for shfl)
  int node = nblk * 32 + g;
  if (node >= NN) return;

  int deg = curp[node << 4];
  if (deg > 64) deg = 64;

  const u16* yfb = yb + (size_t)fb * NN * 32 + l8 * 4;
  const int2* mrow = epk + (size_t)node * 64;

  f32x4 acc0 = ((const f32x4*)bias)[fb * 8 + l8];
  f32x4 acc1 = (f32x4){0.f, 0.f, 0.f, 0.f};

  for (int k = 0; k < deg; k += 8) {
    int2 m = mrow[k + l8];  // one 64B meta line per group (in-bounds: <=63)
#pragma unroll
    for (int j = 0; j < 8; j += 2) {
      if (k + j < deg) {
        int c0 = __shfl(m.x, lw + j);
        float v0 = __int_as_float(__shfl(m.y, lw + j));
        u16x4 u0 = *(const u16x4*)(yfb + (size_t)c0 * 32);
        acc0 += v0 * bf4_to_f32(u0);
      }
      if (k + j + 1 < deg) {
        int c1 = __shfl(m.x, lw + j + 1);
        float v1 = __int_as_float(__shfl(m.y, lw + j + 1));
        u16x4 u1 = *(const u16x4*)(yfb + (size_t)c1 * 32);
        acc1 += v1 * bf4_to_f32(u1);
      }
    }
  }
  acc0 += acc1;
  ((f32x4*)(out + (size_t)node * 256 + fb * 32))[l8] = acc0;
}

// ---- CSR fallback (only if ws too small for padded buckets) ----

__global__ void hist_k(const int* __restrict__ erow, int* __restrict__ off, int E) {
  int e = blockIdx.x * 256 + threadIdx.x;
  if (e < E) atomicAdd(&off[erow[e] + 1], 1);
}

__global__ void scanA_k(int* __restrict__ a, int* __restrict__ blks, int n) {
  __shared__ int s[256];
  int t = threadIdx.x;
  int i = blockIdx.x * 256 + t;
  s[t] = (i < n) ? a[i] : 0;
  __syncthreads();
  for (int d = 1; d < 256; d <<= 1) {
    int v = (t >= d) ? s[t - d] : 0;
    __syncthreads();
    s[t] += v;
    __syncthreads();
  }
  if (i < n) a[i] = s[t];
  if (t == 255) blks[blockIdx.x] = s[255];
}

__global__ void scanB_k(int* __restrict__ a, const int* __restrict__ blks,
                        int* __restrict__ cur, int n, int nn, int nb) {
  __shared__ int s[256];
  int t = threadIdx.x;
  s[t] = (t < nb) ? blks[t] : 0;
  __syncthreads();
  for (int d = 1; d < 256; d <<= 1) {
    int v = (t >= d) ? s[t - d] : 0;
    __syncthreads();
    s[t] += v;
    __syncthreads();
  }
  int prefix = (blockIdx.x == 0) ? 0 : s[blockIdx.x - 1];
  int i = blockIdx.x * 256 + t;
  if (i < n) {
    int v = a[i] + prefix;
    a[i] = v;
    if (i < nn) cur[i] = v;
  }
}

__global__ void scatter_csr_k(const int* __restrict__ erow, const int* __restrict__ ecol,
                              const float* __restrict__ eval, int* __restrict__ cur,
                              int2* __restrict__ epk, int E) {
  int e = blockIdx.x * 256 + threadIdx.x;
  if (e < E) {
    int r = erow[e];
    int p = atomicAdd(&cur[r], 1);
    epk[p] = make_int2(ecol[e], __float_as_int(eval[e]));
  }
}

// wave per node; lane l covers feature f=4l, which in the split layout lives
// at ((l>>3)*NN + col)*32 + (l&7)*4 (fb=l>>3, fi=(l&7)*4).
__global__ void __launch_bounds__(256) gather_csr_k(const int* __restrict__ off,
                                                    const int2* __restrict__ epk,
                                                    const u16* __restrict__ yb,
                                                    const float* __restrict__ bias,
                                                    float* __restrict__ out, int NN) {
  int wave = (int)((blockIdx.x * 256 + threadIdx.x) >> 6);
  int lane = threadIdx.x & 63;
  if (wave >= NN) return;
  int s = off[wave], e = off[wave + 1];

  size_t fbbase = (size_t)(lane >> 3) * NN;
  int fi = (lane & 7) * 4;

  f32x4 acc0 = ((const f32x4*)bias)[lane];
  f32x4 acc1 = (f32x4){0.f, 0.f, 0.f, 0.f};

  int k = s;
  for (; k + 2 <= e; k += 2) {
    int2 p0 = epk[k], p1 = epk[k + 1];
    u16x4 u0 = *(const u16x4*)(yb + (fbbase + p0.x) * 32 + fi);
    u16x4 u1 = *(const u16x4*)(yb + (fbbase + p1.x) * 32 + fi);
    acc0 += __int_as_float(p0.y) * bf4_to_f32(u0);
    acc1 += __int_as_float(p1.y) * bf4_to_f32(u1);
  }
  for (; k < e; k++) {
    int2 p = epk[k];
    u16x4 u = *(const u16x4*)(yb + (fbbase + p.x) * 32 + fi);
    acc0 += __int_as_float(p.y) * bf4_to_f32(u);
  }
  acc0 += acc1;
  ((f32x4*)out)[(size_t)wave * 64 + lane] = acc0;
}

extern "C" void kernel_launch(void* const* d_in, const int* in_sizes, int n_in,
                              void* d_out, int out_size, void* d_ws, size_t ws_size,
                              hipStream_t stream) {
  const float* x    = (const float*)d_in[0];
  const int*   erow = (const int*)d_in[1];
  const int*   ecol = (const int*)d_in[2];
  const float* eval = (const float*)d_in[3];
  const float* Wm   = (const float*)d_in[4];
  const float* bias = (const float*)d_in[5];
  float* out = (float*)d_out;

  int NN = in_sizes[0] / F;  // 50000
  int E  = in_sizes[1];      // 800000

  char* base = (char*)d_ws;
  size_t o = 0;
  auto carve = [&](size_t bytes) {
    void* p = base + o;
    o += (bytes + 255) & ~(size_t)255;
    return p;
  };
  u16* yb   = (u16*)carve((size_t)NN * F * 2);   // 25.6 MB bf16 y (feature-split)
  int* curp = (int*)carve((size_t)NN * 64);      // 3.2 MB: 1 counter per 64B line

  size_t avail = (ws_size > o) ? (ws_size - o) : 0;
  size_t capmax = avail / ((size_t)NN * 8);
  int CAP = 64;  // gather meta-per-lane trick requires exactly 64

  int NT = (NN + 15) / 16;  // 3125 m-tiles

  if (capmax >= 64) {
    // ---- memset -> scatter -> gemm -> gather (all independent until gather) ----
    int2* epk = (int2*)carve((size_t)NN * CAP * 8);
    hipMemsetAsync(curp, 0, (size_t)NN * 64, stream);
    scatter_k<<<(E + 255) / 256, 256, 0, stream>>>(erow, ecol, eval, curp, epk, E, CAP);
    // grid 768 = 3 blocks/CU (144 VGPR caps 3 waves/SIMD): latency hiding vs 512's 2/CU
    gemm_only_k<<<768, 256, 0, stream>>>(x, Wm, yb, NT, NN, 768);
    int nblkN = (NN + 31) / 32;
    gather_fb_k<<<nblkN * 8, 256, 0, stream>>>(curp, epk, yb, bias, out, NN);
  } else {
    // ---- CSR fallback ----
    int*  cur  = curp;
    int*  off  = (int*)carve((size_t)(NN + 1) * 4);
    int*  blks = (int*)carve(256 * 4);
    int2* epk  = (int2*)carve((size_t)E * 8);
    int nOff = NN + 1;
    int nbOff = (nOff + 255) / 256;
    int nbE = (E + 255) / 256;
    hipMemsetAsync(off, 0, (size_t)nOff * 4, stream);
    hist_k<<<nbE, 256, 0, stream>>>(erow, off, E);
    scanA_k<<<nbOff, 256, 0, stream>>>(off, blks, nOff);
    scanB_k<<<nbOff, 256, 0, stream>>>(off, blks, cur, nOff, NN, nbOff);
    scatter_csr_k<<<nbE, 256, 0, stream>>>(erow, ecol, eval, cur, epk, E);
    gemm_only_k<<<768, 256, 0, stream>>>(x, Wm, yb, NT, NN, 768);
    gather_csr_k<<<(NN + 3) / 4, 256, 0, stream>>>(off, epk, yb, bias, out, NN);
  }
}

// Round 4
// 253.309 us; speedup vs baseline: 1.0688x; 1.0688x over previous
//
#include <hip/hip_runtime.h>

typedef unsigned short u16;
typedef __attribute__((ext_vector_type(8))) short short8;
typedef __attribute__((ext_vector_type(4))) float f32x4;
typedef __attribute__((ext_vector_type(4))) u16 u16x4;

#define F 256

__device__ __forceinline__ u16 f2bf(float f) {
  unsigned u = __float_as_uint(f);
  unsigned r = u + 0x7fffu + ((u >> 16) & 1u);
  return (u16)(r >> 16);
}

__device__ __forceinline__ f32x4 bf4_to_f32(u16x4 u) {
  f32x4 x;
#pragma unroll
  for (int j = 0; j < 4; j++) x[j] = __uint_as_float((unsigned)u[j] << 16);
  return x;
}

// ---- GEMM body: y = x @ W^T (bf16 out, row-major), B-resident in registers ----
__device__ __forceinline__ void gemm_body(const float* __restrict__ x,
                                          const float* __restrict__ Wm,
                                          u16* __restrict__ yb,
                                          int NT, int gidx, int stride) {
  int w = (int)(threadIdx.x >> 6);
  int lane = threadIdx.x & 63;
  int ln = lane & 15, q = lane >> 4;

  short8 Bf[4][8];
#pragma unroll
  for (int j = 0; j < 4; j++) {
#pragma unroll
    for (int t = 0; t < 8; t++) {
      const f32x4* wp = (const f32x4*)(Wm + (size_t)((4 * w + j) * 16 + ln) * F + t * 32 + q * 8);
      f32x4 wlo = wp[0], whi = wp[1];
      short8 bfrag;
#pragma unroll
      for (int i = 0; i < 4; i++) {
        bfrag[i]     = (short)f2bf(wlo[i]);
        bfrag[4 + i] = (short)f2bf(whi[i]);
      }
      Bf[j][t] = bfrag;
    }
  }

  for (int mt = gidx; mt < NT; mt += stride) {
    const float* arow = x + (size_t)(mt * 16 + ln) * F + q * 8;
    f32x4 acc[4];
#pragma unroll
    for (int j = 0; j < 4; j++) acc[j] = (f32x4){0.f, 0.f, 0.f, 0.f};

#pragma unroll
    for (int t = 0; t < 8; t++) {
      const f32x4* a4 = (const f32x4*)(arow + t * 32);
      f32x4 alo = a4[0], ahi = a4[1];
      short8 a;
#pragma unroll
      for (int j = 0; j < 4; j++) {
        a[j]     = (short)f2bf(alo[j]);
        a[4 + j] = (short)f2bf(ahi[j]);
      }
#pragma unroll
      for (int j = 0; j < 4; j++) {
        acc[j] = __builtin_amdgcn_mfma_f32_16x16x32_bf16(a, Bf[j][t], acc[j], 0, 0, 0);
      }
    }

    int m0 = mt * 16;
#pragma unroll
    for (int j = 0; j < 4; j++) {
#pragma unroll
      for (int r = 0; r < 4; r++) {
        yb[(size_t)(m0 + q * 4 + r) * F + (4 * w + j) * 16 + ln] = f2bf(acc[j][r]);
      }
    }
  }
}

// Fused gemm || scatter — MEASURED 118.6 us (round 2) vs ~165 us separate.
// ROLE MAPPING MUST BE A CONTIGUOUS RANGE: workgroup->XCD assignment is
// round-robin by blockIdx, so bid<512 spreads gemm blocks 64/XCD, 2/CU
// (same placement as a standalone 512-block gemm dispatch). The round-1
// predicate (bid&7)==0 put all gemm on XCD 0 -> 460 us. Do not "fix" back.
// curp must be zeroed by the preceding hipMemsetAsync node.
#define NGEMM 512
#define NSCAT 3584
__global__ void __launch_bounds__(256, 1) gemmscat_k(const float* __restrict__ x,
                                                     const float* __restrict__ Wm,
                                                     u16* __restrict__ yb, int NT,
                                                     const int* __restrict__ erow,
                                                     const int* __restrict__ ecol,
                                                     const float* __restrict__ eval,
                                                     int* __restrict__ curp,
                                                     int2* __restrict__ epk,
                                                     int E, int CAP) {
  int bid = (int)blockIdx.x;
  if (bid < NGEMM) {
    gemm_body(x, Wm, yb, NT, bid, NGEMM);
  } else {
    int sid = bid - NGEMM;  // 0..NSCAT-1
    for (int e = sid * 256 + (int)threadIdx.x; e < E; e += NSCAT * 256) {
      int r = erow[e];
      int p = atomicAdd(&curp[r << 4], 1);
      if (p < CAP) epk[(size_t)r * CAP + p] = make_int2(ecol[e], __float_as_int(eval[e]));
    }
  }
}

// one wave per node — EXACT round-0 proven form (62.3 us). CAP==64: lane i
// preloads meta i UNCONDITIONALLY (meta load must issue in parallel with the
// curp load — round 2's "lane<degr" predication serialized meta behind deg
// and regressed gather ~2x; do not reintroduce). Per-edge __shfl broadcast
// gives pure-register y-addresses -> 8 independent loads in flight.
__global__ void __launch_bounds__(256) gather_dir_k(const int* __restrict__ curp,
                                                    const int2* __restrict__ epk,
                                                    const u16* __restrict__ yb,
                                                    const float* __restrict__ bias,
                                                    float* __restrict__ out, int NN) {
  int wave = (int)((blockIdx.x * 256 + threadIdx.x) >> 6);
  int lane = threadIdx.x & 63;
  if (wave >= NN) return;
  int deg = curp[wave << 4];
  if (deg > 64) deg = 64;

  int2 m = epk[(size_t)wave * 64 + lane];  // all <=64 metas, one per lane
  int mc = m.x, mv = m.y;
  const u16* ybl = yb + lane * 4;

  f32x4 acc0 = ((const f32x4*)bias)[lane];
  f32x4 acc1 = (f32x4){0.f, 0.f, 0.f, 0.f};
  f32x4 acc2 = (f32x4){0.f, 0.f, 0.f, 0.f};
  f32x4 acc3 = (f32x4){0.f, 0.f, 0.f, 0.f};

  int k = 0;
  for (; k + 8 <= deg; k += 8) {
    int c0 = __shfl(mc, k + 0), c1 = __shfl(mc, k + 1);
    int c2 = __shfl(mc, k + 2), c3 = __shfl(mc, k + 3);
    int c4 = __shfl(mc, k + 4), c5 = __shfl(mc, k + 5);
    int c6 = __shfl(mc, k + 6), c7 = __shfl(mc, k + 7);
    u16x4 u0 = *(const u16x4*)(ybl + (size_t)c0 * F);
    u16x4 u1 = *(const u16x4*)(ybl + (size_t)c1 * F);
    u16x4 u2 = *(const u16x4*)(ybl + (size_t)c2 * F);
    u16x4 u3 = *(const u16x4*)(ybl + (size_t)c3 * F);
    u16x4 u4 = *(const u16x4*)(ybl + (size_t)c4 * F);
    u16x4 u5 = *(const u16x4*)(ybl + (size_t)c5 * F);
    u16x4 u6 = *(const u16x4*)(ybl + (size_t)c6 * F);
    u16x4 u7 = *(const u16x4*)(ybl + (size_t)c7 * F);
    float v0 = __int_as_float(__shfl(mv, k + 0)), v1 = __int_as_float(__shfl(mv, k + 1));
    float v2 = __int_as_float(__shfl(mv, k + 2)), v3 = __int_as_float(__shfl(mv, k + 3));
    float v4 = __int_as_float(__shfl(mv, k + 4)), v5 = __int_as_float(__shfl(mv, k + 5));
    float v6 = __int_as_float(__shfl(mv, k + 6)), v7 = __int_as_float(__shfl(mv, k + 7));
    acc0 += v0 * bf4_to_f32(u0);
    acc1 += v1 * bf4_to_f32(u1);
    acc2 += v2 * bf4_to_f32(u2);
    acc3 += v3 * bf4_to_f32(u3);
    acc0 += v4 * bf4_to_f32(u4);
    acc1 += v5 * bf4_to_f32(u5);
    acc2 += v6 * bf4_to_f32(u6);
    acc3 += v7 * bf4_to_f32(u7);
  }
  for (; k < deg; k++) {
    int c = __shfl(mc, k);
    float v = __int_as_float(__shfl(mv, k));
    u16x4 u = *(const u16x4*)(ybl + (size_t)c * F);
    acc0 += v * bf4_to_f32(u);
  }
  acc0 += acc1;
  acc2 += acc3;
  acc0 += acc2;
  ((f32x4*)out)[(size_t)wave * 64 + lane] = acc0;
}

// ---- CSR fallback (only if ws too small for padded buckets) ----

__global__ void hist_k(const int* __restrict__ erow, int* __restrict__ off, int E) {
  int e = blockIdx.x * 256 + threadIdx.x;
  if (e < E) atomicAdd(&off[erow[e] + 1], 1);
}

__global__ void scanA_k(int* __restrict__ a, int* __restrict__ blks, int n) {
  __shared__ int s[256];
  int t = threadIdx.x;
  int i = blockIdx.x * 256 + t;
  s[t] = (i < n) ? a[i] : 0;
  __syncthreads();
  for (int d = 1; d < 256; d <<= 1) {
    int v = (t >= d) ? s[t - d] : 0;
    __syncthreads();
    s[t] += v;
    __syncthreads();
  }
  if (i < n) a[i] = s[t];
  if (t == 255) blks[blockIdx.x] = s[255];
}

__global__ void scanB_k(int* __restrict__ a, const int* __restrict__ blks,
                        int* __restrict__ cur, int n, int nn, int nb) {
  __shared__ int s[256];
  int t = threadIdx.x;
  s[t] = (t < nb) ? blks[t] : 0;
  __syncthreads();
  for (int d = 1; d < 256; d <<= 1) {
    int v = (t >= d) ? s[t - d] : 0;
    __syncthreads();
    s[t] += v;
    __syncthreads();
  }
  int prefix = (blockIdx.x == 0) ? 0 : s[blockIdx.x - 1];
  int i = blockIdx.x * 256 + t;
  if (i < n) {
    int v = a[i] + prefix;
    a[i] = v;
    if (i < nn) cur[i] = v;
  }
}

__global__ void scatter_csr_k(const int* __restrict__ erow, const int* __restrict__ ecol,
                              const float* __restrict__ eval, int* __restrict__ cur,
                              int2* __restrict__ epk, int E) {
  int e = blockIdx.x * 256 + threadIdx.x;
  if (e < E) {
    int r = erow[e];
    int p = atomicAdd(&cur[r], 1);
    epk[p] = make_int2(ecol[e], __float_as_int(eval[e]));
  }
}

__global__ void __launch_bounds__(256) gather_csr_k(const int* __restrict__ off,
                                                    const int2* __restrict__ epk,
                                                    const u16* __restrict__ yb,
                                                    const float* __restrict__ bias,
                                                    float* __restrict__ out, int NN) {
  int wave = (int)((blockIdx.x * 256 + threadIdx.x) >> 6);
  int lane = threadIdx.x & 63;
  if (wave >= NN) return;
  int s = off[wave], e = off[wave + 1];

  f32x4 acc0 = ((const f32x4*)bias)[lane];
  f32x4 acc1 = (f32x4){0.f, 0.f, 0.f, 0.f};
  f32x4 acc2 = (f32x4){0.f, 0.f, 0.f, 0.f};
  f32x4 acc3 = (f32x4){0.f, 0.f, 0.f, 0.f};

  int k = s;
  for (; k + 4 <= e; k += 4) {
    int2 p0 = epk[k], p1 = epk[k + 1], p2 = epk[k + 2], p3 = epk[k + 3];
    u16x4 u0 = *(const u16x4*)(yb + (size_t)p0.x * F + lane * 4);
    u16x4 u1 = *(const u16x4*)(yb + (size_t)p1.x * F + lane * 4);
    u16x4 u2 = *(const u16x4*)(yb + (size_t)p2.x * F + lane * 4);
    u16x4 u3 = *(const u16x4*)(yb + (size_t)p3.x * F + lane * 4);
    acc0 += __int_as_float(p0.y) * bf4_to_f32(u0);
    acc1 += __int_as_float(p1.y) * bf4_to_f32(u1);
    acc2 += __int_as_float(p2.y) * bf4_to_f32(u2);
    acc3 += __int_as_float(p3.y) * bf4_to_f32(u3);
  }
  for (; k < e; k++) {
    int2 p = epk[k];
    u16x4 u = *(const u16x4*)(yb + (size_t)p.x * F + lane * 4);
    acc0 += __int_as_float(p.y) * bf4_to_f32(u);
  }
  acc0 += acc1;
  acc2 += acc3;
  acc0 += acc2;
  ((f32x4*)out)[(size_t)wave * 64 + lane] = acc0;
}

__global__ void __launch_bounds__(256, 1) gemm_only_k(const float* __restrict__ x,
                                                      const float* __restrict__ Wm,
                                                      u16* __restrict__ yb, int NT, int stride) {
  gemm_body(x, Wm, yb, NT, blockIdx.x, stride);
}

extern "C" void kernel_launch(void* const* d_in, const int* in_sizes, int n_in,
                              void* d_out, int out_size, void* d_ws, size_t ws_size,
                              hipStream_t stream) {
  const float* x    = (const float*)d_in[0];
  const int*   erow = (const int*)d_in[1];
  const int*   ecol = (const int*)d_in[2];
  const float* eval = (const float*)d_in[3];
  const float* Wm   = (const float*)d_in[4];
  const float* bias = (const float*)d_in[5];
  float* out = (float*)d_out;

  int NN = in_sizes[0] / F;  // 50000
  int E  = in_sizes[1];      // 800000

  char* base = (char*)d_ws;
  size_t o = 0;
  auto carve = [&](size_t bytes) {
    void* p = base + o;
    o += (bytes + 255) & ~(size_t)255;
    return p;
  };
  u16* yb   = (u16*)carve((size_t)NN * F * 2);   // 25.6 MB bf16 y (row-major)
  int* curp = (int*)carve((size_t)NN * 64);      // 3.2 MB: 1 counter per 64B line

  size_t avail = (ws_size > o) ? (ws_size - o) : 0;
  size_t capmax = avail / ((size_t)NN * 8);
  int CAP = 64;  // gather meta-per-lane trick requires exactly 64

  int NT = (NN + 15) / 16;  // 3125 m-tiles

  if (capmax >= 64) {
    // ---- memset -> fused gemm||scatter (118.6 us) -> gather (62.3 us) ----
    int2* epk = (int2*)carve((size_t)NN * CAP * 8);
    hipMemsetAsync(curp, 0, (size_t)NN * 64, stream);
    gemmscat_k<<<NGEMM + NSCAT, 256, 0, stream>>>(x, Wm, yb, NT, erow, ecol, eval, curp, epk, E, CAP);
    gather_dir_k<<<(NN + 3) / 4, 256, 0, stream>>>(curp, epk, yb, bias, out, NN);
  } else {
    // ---- CSR fallback ----
    int*  cur  = curp;
    int*  off  = (int*)carve((size_t)(NN + 1) * 4);
    int*  blks = (int*)carve(256 * 4);
    int2* epk  = (int2*)carve((size_t)E * 8);
    int nOff = NN + 1;
    int nbOff = (nOff + 255) / 256;
    int nbE = (E + 255) / 256;
    hipMemsetAsync(off, 0, (size_t)nOff * 4, stream);
    hist_k<<<nbE, 256, 0, stream>>>(erow, off, E);
    scanA_k<<<nbOff, 256, 0, stream>>>(off, blks, nOff);
    scanB_k<<<nbOff, 256, 0, stream>>>(off, blks, cur, nOff, NN, nbOff);
    scatter_csr_k<<<nbE, 256, 0, stream>>>(erow, ecol, eval, cur, epk, E);
    gemm_only_k<<<512, 256, 0, stream>>>(x, Wm, yb, NT, 512);
    gather_csr_k<<<(NN + 3) / 4, 256, 0, stream>>>(off, epk, yb, bias, out, NN);
  }
}

// Round 5
// 252.281 us; speedup vs baseline: 1.0732x; 1.0041x over previous
//
#include <hip/hip_runtime.h>

typedef unsigned short u16;
typedef __attribute__((ext_vector_type(8))) short short8;
typedef __attribute__((ext_vector_type(8))) u16 u16x8;
typedef __attribute__((ext_vector_type(4))) float f32x4;
typedef __attribute__((ext_vector_type(4))) u16 u16x4;

#define F 256
#define GB 256   // gemm grid: 1 block/CU (LDS-capped anyway)
#define GT 512   // gemm block threads: 8 waves

__device__ __forceinline__ u16 f2bf(float f) {
  unsigned u = __float_as_uint(f);
  unsigned r = u + 0x7fffu + ((u >> 16) & 1u);
  return (u16)(r >> 16);
}

__device__ __forceinline__ f32x4 bf4_to_f32(u16x4 u) {
  f32x4 x;
#pragma unroll
  for (int j = 0; j < 4; j++) x[j] = __uint_as_float((unsigned)u[j] << 16);
  return x;
}

// ---- GEMM: y = x @ W^T (bf16 out, row-major), B in LDS (128 KB) ----
// Why LDS-B: the register-B version (Bf[4][8] = 128 VGPR, 144 total) capped
// residency at 1x256-thread block/CU = 8 waves/CU = 25% occupancy -> the x
// loads couldn't be latency-hidden (~55-62 us vs ~15 us roofline). LDS-B at
// ~64 VGPR + 512-thread blocks gives 16 waves/CU.
// LDS swizzle: byte ^= (row&7)<<4. Unswizzled, a quarter-wave's 16 ln-lanes
// read the same 4-bank set (16-way conflict); swizzled each quarter-wave
// spreads 2-deep across all 32 banks (2-way = free). Write side applies the
// same XOR (both-sides-or-neither).
// Also folds the zeroing of the padded scatter counters (dispatch boundary
// orders it before scatter's atomics).
__global__ void __launch_bounds__(GT, 1) gemmzero_k(const float* __restrict__ x,
                                                    const float* __restrict__ Wm,
                                                    u16* __restrict__ yb, int NT,
                                                    int4* __restrict__ zp, int zeroN4) {
  // folded counter zeroing
  int tid = (int)blockIdx.x * GT + (int)threadIdx.x;
  for (int i = tid; i < zeroN4; i += GB * GT) zp[i] = make_int4(0, 0, 0, 0);

  __shared__ u16 Bs[F * F];  // 128 KB: full W as bf16, swizzled

  // stage W (f32, row-major [outcol][k]) -> LDS bf16. 8192 16B-chunks.
  for (int ch = (int)threadIdx.x; ch < F * 32; ch += GT) {
    int r = ch >> 5, cc = ch & 31;
    const f32x4* wp = (const f32x4*)(Wm + (size_t)r * F + cc * 8);
    f32x4 lo = wp[0], hi = wp[1];
    u16x8 v;
#pragma unroll
    for (int i = 0; i < 4; i++) {
      v[i]     = f2bf(lo[i]);
      v[4 + i] = f2bf(hi[i]);
    }
    unsigned sw = (unsigned)(r * 512 + cc * 16) ^ (unsigned)((r & 7) << 4);
    *(u16x8*)((char*)Bs + sw) = v;
  }
  __syncthreads();

  int w = (int)(threadIdx.x >> 6);   // wave 0..7 -> col-groups 2w, 2w+1
  int lane = threadIdx.x & 63;
  int ln = lane & 15, q = lane >> 4;
  int row0 = (2 * w) * 16 + ln;      // row&7 == ln&7 (16-aligned base)
  const char* bsl = (const char*)Bs;
  unsigned swl = (unsigned)((ln & 7) << 4);

  for (int mt = (int)blockIdx.x; mt < NT; mt += GB) {
    const float* arow = x + (size_t)(mt * 16 + ln) * F + q * 8;
    f32x4 acc0 = (f32x4){0.f, 0.f, 0.f, 0.f};
    f32x4 acc1 = (f32x4){0.f, 0.f, 0.f, 0.f};

#pragma unroll
    for (int t = 0; t < 8; t++) {
      const f32x4* a4 = (const f32x4*)(arow + t * 32);
      f32x4 alo = a4[0], ahi = a4[1];
      short8 a;
#pragma unroll
      for (int j = 0; j < 4; j++) {
        a[j]     = (short)f2bf(alo[j]);
        a[4 + j] = (short)f2bf(ahi[j]);
      }
      unsigned sb = ((unsigned)(t * 64 + q * 16)) ^ swl;
      short8 b0 = *(const short8*)(bsl + row0 * 512 + sb);
      short8 b1 = *(const short8*)(bsl + (row0 + 16) * 512 + sb);
      acc0 = __builtin_amdgcn_mfma_f32_16x16x32_bf16(a, b0, acc0, 0, 0, 0);
      acc1 = __builtin_amdgcn_mfma_f32_16x16x32_bf16(a, b1, acc1, 0, 0, 0);
    }

    int m0 = mt * 16;
#pragma unroll
    for (int r = 0; r < 4; r++) {
      yb[(size_t)(m0 + q * 4 + r) * F + (2 * w) * 16 + ln]       = f2bf(acc0[r]);
      yb[(size_t)(m0 + q * 4 + r) * F + (2 * w + 1) * 16 + ln]   = f2bf(acc1[r]);
    }
  }
}

// 1 edge/thread; counters padded to one per 64B line (r<<4) — exact round-0 form.
__global__ void __launch_bounds__(256) scatter_k(const int* __restrict__ erow,
                                                 const int* __restrict__ ecol,
                                                 const float* __restrict__ eval,
                                                 int* __restrict__ curp,
                                                 int2* __restrict__ epk, int E, int CAP) {
  int e = blockIdx.x * 256 + (int)threadIdx.x;
  if (e < E) {
    int r = erow[e];
    int p = atomicAdd(&curp[r << 4], 1);
    if (p < CAP) epk[(size_t)r * CAP + p] = make_int2(ecol[e], __float_as_int(eval[e]));
  }
}

// one wave per node — exact round-0 proven form (62.3 us). CAP==64: lane i
// preloads meta i unconditionally (issues in parallel with the curp load);
// per-edge __shfl broadcast gives pure-register y-addresses -> 8 loads in flight.
__global__ void __launch_bounds__(256) gather_dir_k(const int* __restrict__ curp,
                                                    const int2* __restrict__ epk,
                                                    const u16* __restrict__ yb,
                                                    const float* __restrict__ bias,
                                                    float* __restrict__ out, int NN) {
  int wave = (int)((blockIdx.x * 256 + threadIdx.x) >> 6);
  int lane = threadIdx.x & 63;
  if (wave >= NN) return;
  int deg = curp[wave << 4];
  if (deg > 64) deg = 64;

  int2 m = epk[(size_t)wave * 64 + lane];  // all <=64 metas, one per lane
  int mc = m.x, mv = m.y;
  const u16* ybl = yb + lane * 4;

  f32x4 acc0 = ((const f32x4*)bias)[lane];
  f32x4 acc1 = (f32x4){0.f, 0.f, 0.f, 0.f};
  f32x4 acc2 = (f32x4){0.f, 0.f, 0.f, 0.f};
  f32x4 acc3 = (f32x4){0.f, 0.f, 0.f, 0.f};

  int k = 0;
  for (; k + 8 <= deg; k += 8) {
    int c0 = __shfl(mc, k + 0), c1 = __shfl(mc, k + 1);
    int c2 = __shfl(mc, k + 2), c3 = __shfl(mc, k + 3);
    int c4 = __shfl(mc, k + 4), c5 = __shfl(mc, k + 5);
    int c6 = __shfl(mc, k + 6), c7 = __shfl(mc, k + 7);
    u16x4 u0 = *(const u16x4*)(ybl + (size_t)c0 * F);
    u16x4 u1 = *(const u16x4*)(ybl + (size_t)c1 * F);
    u16x4 u2 = *(const u16x4*)(ybl + (size_t)c2 * F);
    u16x4 u3 = *(const u16x4*)(ybl + (size_t)c3 * F);
    u16x4 u4 = *(const u16x4*)(ybl + (size_t)c4 * F);
    u16x4 u5 = *(const u16x4*)(ybl + (size_t)c5 * F);
    u16x4 u6 = *(const u16x4*)(ybl + (size_t)c6 * F);
    u16x4 u7 = *(const u16x4*)(ybl + (size_t)c7 * F);
    float v0 = __int_as_float(__shfl(mv, k + 0)), v1 = __int_as_float(__shfl(mv, k + 1));
    float v2 = __int_as_float(__shfl(mv, k + 2)), v3 = __int_as_float(__shfl(mv, k + 3));
    float v4 = __int_as_float(__shfl(mv, k + 4)), v5 = __int_as_float(__shfl(mv, k + 5));
    float v6 = __int_as_float(__shfl(mv, k + 6)), v7 = __int_as_float(__shfl(mv, k + 7));
    acc0 += v0 * bf4_to_f32(u0);
    acc1 += v1 * bf4_to_f32(u1);
    acc2 += v2 * bf4_to_f32(u2);
    acc3 += v3 * bf4_to_f32(u3);
    acc0 += v4 * bf4_to_f32(u4);
    acc1 += v5 * bf4_to_f32(u5);
    acc2 += v6 * bf4_to_f32(u6);
    acc3 += v7 * bf4_to_f32(u7);
  }
  for (; k < deg; k++) {
    int c = __shfl(mc, k);
    float v = __int_as_float(__shfl(mv, k));
    u16x4 u = *(const u16x4*)(ybl + (size_t)c * F);
    acc0 += v * bf4_to_f32(u);
  }
  acc0 += acc1;
  acc2 += acc3;
  acc0 += acc2;
  ((f32x4*)out)[(size_t)wave * 64 + lane] = acc0;
}

// ---- CSR fallback (only if ws too small for padded buckets) ----

__device__ __forceinline__ void gemm_body(const float* __restrict__ x,
                                          const float* __restrict__ Wm,
                                          u16* __restrict__ yb,
                                          int NT, int gidx, int stride) {
  int w = (int)(threadIdx.x >> 6);
  int lane = threadIdx.x & 63;
  int ln = lane & 15, q = lane >> 4;

  short8 Bf[4][8];
#pragma unroll
  for (int j = 0; j < 4; j++) {
#pragma unroll
    for (int t = 0; t < 8; t++) {
      const f32x4* wp = (const f32x4*)(Wm + (size_t)((4 * w + j) * 16 + ln) * F + t * 32 + q * 8);
      f32x4 wlo = wp[0], whi = wp[1];
      short8 bfrag;
#pragma unroll
      for (int i = 0; i < 4; i++) {
        bfrag[i]     = (short)f2bf(wlo[i]);
        bfrag[4 + i] = (short)f2bf(whi[i]);
      }
      Bf[j][t] = bfrag;
    }
  }

  for (int mt = gidx; mt < NT; mt += stride) {
    const float* arow = x + (size_t)(mt * 16 + ln) * F + q * 8;
    f32x4 acc[4];
#pragma unroll
    for (int j = 0; j < 4; j++) acc[j] = (f32x4){0.f, 0.f, 0.f, 0.f};

#pragma unroll
    for (int t = 0; t < 8; t++) {
      const f32x4* a4 = (const f32x4*)(arow + t * 32);
      f32x4 alo = a4[0], ahi = a4[1];
      short8 a;
#pragma unroll
      for (int j = 0; j < 4; j++) {
        a[j]     = (short)f2bf(alo[j]);
        a[4 + j] = (short)f2bf(ahi[j]);
      }
#pragma unroll
      for (int j = 0; j < 4; j++) {
        acc[j] = __builtin_amdgcn_mfma_f32_16x16x32_bf16(a, Bf[j][t], acc[j], 0, 0, 0);
      }
    }

    int m0 = mt * 16;
#pragma unroll
    for (int j = 0; j < 4; j++) {
#pragma unroll
      for (int r = 0; r < 4; r++) {
        yb[(size_t)(m0 + q * 4 + r) * F + (4 * w + j) * 16 + ln] = f2bf(acc[j][r]);
      }
    }
  }
}

__global__ void hist_k(const int* __restrict__ erow, int* __restrict__ off, int E) {
  int e = blockIdx.x * 256 + threadIdx.x;
  if (e < E) atomicAdd(&off[erow[e] + 1], 1);
}

__global__ void scanA_k(int* __restrict__ a, int* __restrict__ blks, int n) {
  __shared__ int s[256];
  int t = threadIdx.x;
  int i = blockIdx.x * 256 + t;
  s[t] = (i < n) ? a[i] : 0;
  __syncthreads();
  for (int d = 1; d < 256; d <<= 1) {
    int v = (t >= d) ? s[t - d] : 0;
    __syncthreads();
    s[t] += v;
    __syncthreads();
  }
  if (i < n) a[i] = s[t];
  if (t == 255) blks[blockIdx.x] = s[255];
}

__global__ void scanB_k(int* __restrict__ a, const int* __restrict__ blks,
                        int* __restrict__ cur, int n, int nn, int nb) {
  __shared__ int s[256];
  int t = threadIdx.x;
  s[t] = (t < nb) ? blks[t] : 0;
  __syncthreads();
  for (int d = 1; d < 256; d <<= 1) {
    int v = (t >= d) ? s[t - d] : 0;
    __syncthreads();
    s[t] += v;
    __syncthreads();
  }
  int prefix = (blockIdx.x == 0) ? 0 : s[blockIdx.x - 1];
  int i = blockIdx.x * 256 + t;
  if (i < n) {
    int v = a[i] + prefix;
    a[i] = v;
    if (i < nn) cur[i] = v;
  }
}

__global__ void scatter_csr_k(const int* __restrict__ erow, const int* __restrict__ ecol,
                              const float* __restrict__ eval, int* __restrict__ cur,
                              int2* __restrict__ epk, int E) {
  int e = blockIdx.x * 256 + threadIdx.x;
  if (e < E) {
    int r = erow[e];
    int p = atomicAdd(&cur[r], 1);
    epk[p] = make_int2(ecol[e], __float_as_int(eval[e]));
  }
}

__global__ void __launch_bounds__(256) gather_csr_k(const int* __restrict__ off,
                                                    const int2* __restrict__ epk,
                                                    const u16* __restrict__ yb,
                                                    const float* __restrict__ bias,
                                                    float* __restrict__ out, int NN) {
  int wave = (int)((blockIdx.x * 256 + threadIdx.x) >> 6);
  int lane = threadIdx.x & 63;
  if (wave >= NN) return;
  int s = off[wave], e = off[wave + 1];

  f32x4 acc0 = ((const f32x4*)bias)[lane];
  f32x4 acc1 = (f32x4){0.f, 0.f, 0.f, 0.f};
  f32x4 acc2 = (f32x4){0.f, 0.f, 0.f, 0.f};
  f32x4 acc3 = (f32x4){0.f, 0.f, 0.f, 0.f};

  int k = s;
  for (; k + 4 <= e; k += 4) {
    int2 p0 = epk[k], p1 = epk[k + 1], p2 = epk[k + 2], p3 = epk[k + 3];
    u16x4 u0 = *(const u16x4*)(yb + (size_t)p0.x * F + lane * 4);
    u16x4 u1 = *(const u16x4*)(yb + (size_t)p1.x * F + lane * 4);
    u16x4 u2 = *(const u16x4*)(yb + (size_t)p2.x * F + lane * 4);
    u16x4 u3 = *(const u16x4*)(yb + (size_t)p3.x * F + lane * 4);
    acc0 += __int_as_float(p0.y) * bf4_to_f32(u0);
    acc1 += __int_as_float(p1.y) * bf4_to_f32(u1);
    acc2 += __int_as_float(p2.y) * bf4_to_f32(u2);
    acc3 += __int_as_float(p3.y) * bf4_to_f32(u3);
  }
  for (; k < e; k++) {
    int2 p = epk[k];
    u16x4 u = *(const u16x4*)(yb + (size_t)p.x * F + lane * 4);
    acc0 += __int_as_float(p.y) * bf4_to_f32(u);
  }
  acc0 += acc1;
  acc2 += acc3;
  acc0 += acc2;
  ((f32x4*)out)[(size_t)wave * 64 + lane] = acc0;
}

__global__ void __launch_bounds__(256, 1) gemm_only_k(const float* __restrict__ x,
                                                      const float* __restrict__ Wm,
                                                      u16* __restrict__ yb, int NT, int stride) {
  gemm_body(x, Wm, yb, NT, blockIdx.x, stride);
}

extern "C" void kernel_launch(void* const* d_in, const int* in_sizes, int n_in,
                              void* d_out, int out_size, void* d_ws, size_t ws_size,
                              hipStream_t stream) {
  const float* x    = (const float*)d_in[0];
  const int*   erow = (const int*)d_in[1];
  const int*   ecol = (const int*)d_in[2];
  const float* eval = (const float*)d_in[3];
  const float* Wm   = (const float*)d_in[4];
  const float* bias = (const float*)d_in[5];
  float* out = (float*)d_out;

  int NN = in_sizes[0] / F;  // 50000
  int E  = in_sizes[1];      // 800000

  char* base = (char*)d_ws;
  size_t o = 0;
  auto carve = [&](size_t bytes) {
    void* p = base + o;
    o += (bytes + 255) & ~(size_t)255;
    return p;
  };
  u16* yb   = (u16*)carve((size_t)NN * F * 2);   // 25.6 MB bf16 y (row-major)
  int* curp = (int*)carve((size_t)NN * 64);      // 3.2 MB: 1 counter per 64B line

  size_t avail = (ws_size > o) ? (ws_size - o) : 0;
  size_t capmax = avail / ((size_t)NN * 8);
  int CAP = 64;  // gather meta-per-lane trick requires exactly 64

  int NT = (NN + 15) / 16;  // 3125 m-tiles

  if (capmax >= 64) {
    // ---- round-0 structure: gemm+zero -> scatter -> gather ----
    int2* epk = (int2*)carve((size_t)NN * CAP * 8);
    int zeroN4 = NN * 16 / 4;  // 3.2 MB as int4s
    gemmzero_k<<<GB, GT, 0, stream>>>(x, Wm, yb, NT, (int4*)curp, zeroN4);
    scatter_k<<<(E + 255) / 256, 256, 0, stream>>>(erow, ecol, eval, curp, epk, E, CAP);
    gather_dir_k<<<(NN + 3) / 4, 256, 0, stream>>>(curp, epk, yb, bias, out, NN);
  } else {
    // ---- CSR fallback ----
    int*  cur  = curp;
    int*  off  = (int*)carve((size_t)(NN + 1) * 4);
    int*  blks = (int*)carve(256 * 4);
    int2* epk  = (int2*)carve((size_t)E * 8);
    int nOff = NN + 1;
    int nbOff = (nOff + 255) / 256;
    int nbE = (E + 255) / 256;
    hipMemsetAsync(off, 0, (size_t)nOff * 4, stream);
    hist_k<<<nbE, 256, 0, stream>>>(erow, off, E);
    scanA_k<<<nbOff, 256, 0, stream>>>(off, blks, nOff);
    scanB_k<<<nbOff, 256, 0, stream>>>(off, blks, cur, nOff, NN, nbOff);
    scatter_csr_k<<<nbE, 256, 0, stream>>>(erow, ecol, eval, cur, epk, E);
    gemm_only_k<<<512, 256, 0, stream>>>(x, Wm, yb, NT, 512);
    gather_csr_k<<<(NN + 3) / 4, 256, 0, stream>>>(off, epk, yb, bias, out, NN);
  }
}